// Round 8
// baseline (196.259 us; speedup 1.0000x reference)
//
#include <hip/hip_runtime.h>

// ModuleCollect: out[i] = concat(x[i], masked_gather(x, idx[i,0..3]))
// x: [N, 256] f32, indices: [N,4] int (-1 = masked -> zeros), out: [N, 1280] f32
//
// Edge-list formulation with src-segment locality:
//  - 400k gather edges bucketed by src segment (S=16 segments, 6.4 MB each)
//  - edge kernel processes segments in block order: gather reads hit a
//    MALL-resident 6.4 MB working set (~4x reuse per row), writes are
//    nt 1KB bursts in ~ascending dest order
//  - self-copy + masked-zero-fill is a separate sequential all-nt pass
// Measured facts driving this: random 1KB READS run at wire speed
// (fwd kernel, 6.87 TB/s); random 1KB WRITES do not (~4.3 TB/s, r6/r7);
// coarse S=2 segmentation gave no cache help (r5).
// Atomic bucket order is nondeterministic but the (dest,slot)->value map
// is exact, so d_out is deterministic. Counts re-zeroed every call.

typedef float f32x4 __attribute__((ext_vector_type(4)));

#define D 256
#define D4 (D / 4)         // 64 f32x4 per x row
#define OUTW4 (5 * D / 4)  // 320 f32x4 per out row
#define S 16               // src segments
#define BPS 8192           // edge-kernel blocks per segment
#define CAP (BPS * 4)      // 32768 edge slots per segment (mean ~25000, +50 sigma)

__global__ __launch_bounds__(64) void zero_counts_kernel(int* seg_cnt)
{
    if (threadIdx.x < S) seg_cnt[threadIdx.x] = 0;
}

__global__ __launch_bounds__(256) void build_edges_kernel(
    const int* __restrict__ indices, int n4, int segrows,
    int* seg_cnt, uint2* __restrict__ ebuf)
{
    __shared__ int lcnt[S];
    __shared__ int lbase[S];
    if (threadIdx.x < S) lcnt[threadIdx.x] = 0;
    __syncthreads();

    const int e = blockIdx.x * 256 + threadIdx.x;
    int t = -1, seg = 0, pos = 0;
    if (e < n4) t = indices[e];
    if (t >= 0) {
        seg = t / segrows;
        pos = atomicAdd(&lcnt[seg], 1);
    }
    __syncthreads();
    if (threadIdx.x < S) {
        int c = lcnt[threadIdx.x];
        lbase[threadIdx.x] = c ? atomicAdd(&seg_cnt[threadIdx.x], c) : 0;
    }
    __syncthreads();
    if (t >= 0) {
        int p = lbase[seg] + pos;
        if (p < CAP)
            ebuf[(long)seg * CAP + p] = make_uint2((unsigned)e, (unsigned)t);
    }
}

__global__ __launch_bounds__(256) void self_copy_kernel(
    const f32x4* __restrict__ x4, const int* __restrict__ indices,
    f32x4* __restrict__ out4, int n)
{
    const int wave = threadIdx.x >> 6;
    const int lane = threadIdx.x & 63;
    const int row  = blockIdx.x * 4 + wave;
    if (row >= n) return;

    f32x4 v = __builtin_nontemporal_load(&x4[(long)row * D4 + lane]);
    __builtin_nontemporal_store(v, &out4[(long)row * OUTW4 + lane]);

    const f32x4 zero = (f32x4){0.f, 0.f, 0.f, 0.f};
    #pragma unroll
    for (int s = 0; s < 4; ++s) {
        if (indices[row * 4 + s] < 0)
            __builtin_nontemporal_store(zero,
                &out4[(long)row * OUTW4 + (1 + s) * D4 + lane]);
    }
}

__global__ __launch_bounds__(256) void edge_scatter_kernel(
    const f32x4* __restrict__ x4, const int* __restrict__ seg_cnt,
    const uint2* __restrict__ ebuf, f32x4* __restrict__ out4)
{
    const int wv   = threadIdx.x >> 6;
    const int lane = threadIdx.x & 63;
    const int seg    = blockIdx.x >> 13;        // / BPS
    const int within = blockIdx.x & (BPS - 1);
    const int eidx = within * 4 + wv;

    int cnt = seg_cnt[seg];
    if (cnt > CAP) cnt = CAP;
    if (eidx >= cnt) return;

    const uint2 ed = ebuf[(long)seg * CAP + eidx];
    const int e = (int)ed.x, src = (int)ed.y;
    const int dest = e >> 2, slot = e & 3;

    // normal cached load: src segment (6.4 MB) should be MALL-resident
    f32x4 v = x4[(long)src * D4 + lane];
    __builtin_nontemporal_store(v,
        &out4[(long)dest * OUTW4 + (1 + slot) * D4 + lane]);
}

// ---- fallback: plain forward kernel ----
__global__ __launch_bounds__(256) void collect_fwd_kernel(
    const f32x4* __restrict__ x4, const int* __restrict__ indices,
    f32x4* __restrict__ out4, int n)
{
    const int wave = threadIdx.x >> 6;
    const int lane = threadIdx.x & 63;
    const int row  = blockIdx.x * 4 + wave;
    if (row >= n) return;
    const f32x4* xrow = x4 + (long)row * D4;
    f32x4* orow = out4 + (long)row * OUTW4;
    const int i0 = indices[row * 4 + 0];
    const int i1 = indices[row * 4 + 1];
    const int i2 = indices[row * 4 + 2];
    const int i3 = indices[row * 4 + 3];
    const f32x4 zero = (f32x4){0.f, 0.f, 0.f, 0.f};
    f32x4 v_self = xrow[lane];
    f32x4 v0 = (i0 >= 0) ? x4[(long)i0 * D4 + lane] : zero;
    f32x4 v1 = (i1 >= 0) ? x4[(long)i1 * D4 + lane] : zero;
    f32x4 v2 = (i2 >= 0) ? x4[(long)i2 * D4 + lane] : zero;
    f32x4 v3 = (i3 >= 0) ? x4[(long)i3 * D4 + lane] : zero;
    __builtin_nontemporal_store(v_self, &orow[lane]);
    __builtin_nontemporal_store(v0, &orow[D4 * 1 + lane]);
    __builtin_nontemporal_store(v1, &orow[D4 * 2 + lane]);
    __builtin_nontemporal_store(v2, &orow[D4 * 3 + lane]);
    __builtin_nontemporal_store(v3, &orow[D4 * 4 + lane]);
}

extern "C" void kernel_launch(void* const* d_in, const int* in_sizes, int n_in,
                              void* d_out, int out_size, void* d_ws, size_t ws_size,
                              hipStream_t stream)
{
    const f32x4* x4 = (const f32x4*)d_in[0];
    const int* indices = (const int*)d_in[1];
    f32x4* out4 = (f32x4*)d_out;

    const int n  = in_sizes[0] / D;   // 100000
    const int n4 = in_sizes[1];       // 400000
    const int segrows = (n + S - 1) / S;  // 6250

    // ws layout
    size_t off_cnt  = 0;                         // S ints
    size_t off_ebuf = 64;                        // S*CAP uint2
    size_t need = off_ebuf + (size_t)S * CAP * sizeof(uint2);  // ~4.2 MB

    dim3 block(256);

    if (ws_size < need) {
        collect_fwd_kernel<<<dim3((n + 3) / 4), block, 0, stream>>>(x4, indices, out4, n);
        return;
    }

    char* ws = (char*)d_ws;
    int*   seg_cnt = (int*)(ws + off_cnt);
    uint2* ebuf    = (uint2*)(ws + off_ebuf);

    zero_counts_kernel<<<dim3(1), dim3(64), 0, stream>>>(seg_cnt);
    build_edges_kernel<<<dim3((n4 + 255) / 256), block, 0, stream>>>(
        indices, n4, segrows, seg_cnt, ebuf);
    self_copy_kernel<<<dim3((n + 3) / 4), block, 0, stream>>>(x4, indices, out4, n);
    edge_scatter_kernel<<<dim3(S * BPS), block, 0, stream>>>(x4, seg_cnt, ebuf, out4);
}

// Round 9
// 145.702 us; speedup vs baseline: 1.3470x; 1.3470x over previous
//
#include <hip/hip_runtime.h>

// ModuleCollect: out[i] = concat(x[i], masked_gather(x, idx[i,0..3]))
// x: [N, 256] f32, indices: [N,4] int (-1 = masked -> zeros), out: [N, 1280] f32
//
// MEASURED-BEST variant (round 6, 145.8 us): inverted-index scatter.
// Reads x exactly once (102 MB); scatters each source row to its
// referencing output segments (all stores non-temporal).
// Traffic: 512 MB W + 102 MB R + ~16 MB aux ~= 630 MB @ ~4.3 TB/s
// (random-1KB-write limited).
//
// Session evidence (r3-r8):
//  - forward gather (random reads, seq writes): 149.8 us = 1.03 GB @ 6.85 TB/s
//    (wire speed; random 1KB READS are full-rate)
//  - random 1KB WRITES cap at ~4.3 TB/s under nt AND normal policy (r6/r7)
//  - MALL read-reuse unobtainable: S=2 pass null (r5), nt-load null (r4),
//    S=16 edge-list regressed on write randomness (r8)
// Both formulations sit at their respective wire-speed limits; this one
// is 2.7% faster. ~146 us is the practical roofline for this op.

typedef float f32x4 __attribute__((ext_vector_type(4)));

#define D 256
#define D4 (D / 4)        // 64 f32x4 per row of x
#define OUTW4 (5 * D / 4) // 320 f32x4 per output row
#define CAP 16            // bucket capacity; Poisson(4) tail beyond 16 ~ 5e-6/row
#define OVF_CAP 65536

__global__ __launch_bounds__(256) void zero_counts_kernel(int* counts, int* ovf_cnt, int n)
{
    int i = blockIdx.x * blockDim.x + threadIdx.x;
    if (i == 0) *ovf_cnt = 0;
    if (i < n) counts[i] = 0;
}

__global__ __launch_bounds__(256) void build_buckets_kernel(
    const int* __restrict__ indices, int* counts, int* buckets,
    int* ovf, int* ovf_cnt, int n4)
{
    int e = blockIdx.x * blockDim.x + threadIdx.x;
    if (e >= n4) return;
    int t = indices[e];
    if (t < 0) return;
    int pos = atomicAdd(&counts[t], 1);
    if (pos < CAP) {
        buckets[t * CAP + pos] = e;      // e encodes dest*4+slot
    } else {
        int o = atomicAdd(ovf_cnt, 1);
        if (o < OVF_CAP) ovf[o] = e;
    }
}

__global__ __launch_bounds__(256) void scatter_kernel(
    const f32x4* __restrict__ x4,       // [N * 64]
    const int*   __restrict__ indices,  // [N * 4]
    const int*   __restrict__ counts,
    const int*   __restrict__ buckets,
    f32x4*       __restrict__ out4,     // [N * 320]
    int n)
{
    const int wave = threadIdx.x >> 6;
    const int lane = threadIdx.x & 63;
    const int r = blockIdx.x * 4 + wave;
    if (r >= n) return;

    // source row, read exactly once kernel-wide
    const f32x4 v = __builtin_nontemporal_load(&x4[(long)r * D4 + lane]);

    // self segment
    __builtin_nontemporal_store(v, &out4[(long)r * OUTW4 + lane]);

    // zero-fill own masked slots (rare: P(idx==-1) ~ 1e-5)
    const f32x4 zero = (f32x4){0.f, 0.f, 0.f, 0.f};
    #pragma unroll
    for (int s = 0; s < 4; ++s) {
        if (indices[r * 4 + s] < 0)
            __builtin_nontemporal_store(zero, &out4[(long)r * OUTW4 + (1 + s) * D4 + lane]);
    }

    // scatter to referencing outputs
    int cnt = counts[r];
    if (cnt > CAP) cnt = CAP;
    for (int j = 0; j < cnt; ++j) {
        int e = buckets[r * CAP + j];
        int dest = e >> 2, slot = e & 3;
        __builtin_nontemporal_store(v, &out4[(long)dest * OUTW4 + (1 + slot) * D4 + lane]);
    }
}

__global__ __launch_bounds__(256) void overflow_fixup_kernel(
    const f32x4* __restrict__ x4, const int* __restrict__ indices,
    const int* __restrict__ ovf, const int* __restrict__ ovf_cnt,
    f32x4* __restrict__ out4)
{
    const int wave = threadIdx.x >> 6;
    const int lane = threadIdx.x & 63;
    const int gw = blockIdx.x * 4 + wave;
    const int nwaves = gridDim.x * 4;
    int cnt = *ovf_cnt;
    if (cnt > OVF_CAP) cnt = OVF_CAP;
    for (int i = gw; i < cnt; i += nwaves) {
        int e = ovf[i];
        int row = e >> 2, slot = e & 3;
        int t = indices[e];                      // >= 0 by construction
        f32x4 v = x4[(long)t * D4 + lane];
        __builtin_nontemporal_store(v, &out4[(long)row * OUTW4 + (1 + slot) * D4 + lane]);
    }
}

// ---- fallback: plain forward kernel (round-3 version, 149.8 us) ----
__global__ __launch_bounds__(256) void collect_fwd_kernel(
    const f32x4* __restrict__ x4, const int* __restrict__ indices,
    f32x4* __restrict__ out4, int n)
{
    const int wave = threadIdx.x >> 6;
    const int lane = threadIdx.x & 63;
    const int row  = blockIdx.x * 4 + wave;
    if (row >= n) return;
    const f32x4* xrow = x4 + (long)row * D4;
    f32x4* orow = out4 + (long)row * OUTW4;
    const int i0 = indices[row * 4 + 0];
    const int i1 = indices[row * 4 + 1];
    const int i2 = indices[row * 4 + 2];
    const int i3 = indices[row * 4 + 3];
    const f32x4 zero = (f32x4){0.f, 0.f, 0.f, 0.f};
    f32x4 v_self = xrow[lane];
    f32x4 v0 = (i0 >= 0) ? x4[(long)i0 * D4 + lane] : zero;
    f32x4 v1 = (i1 >= 0) ? x4[(long)i1 * D4 + lane] : zero;
    f32x4 v2 = (i2 >= 0) ? x4[(long)i2 * D4 + lane] : zero;
    f32x4 v3 = (i3 >= 0) ? x4[(long)i3 * D4 + lane] : zero;
    __builtin_nontemporal_store(v_self, &orow[lane]);
    __builtin_nontemporal_store(v0, &orow[D4 * 1 + lane]);
    __builtin_nontemporal_store(v1, &orow[D4 * 2 + lane]);
    __builtin_nontemporal_store(v2, &orow[D4 * 3 + lane]);
    __builtin_nontemporal_store(v3, &orow[D4 * 4 + lane]);
}

extern "C" void kernel_launch(void* const* d_in, const int* in_sizes, int n_in,
                              void* d_out, int out_size, void* d_ws, size_t ws_size,
                              hipStream_t stream)
{
    const f32x4* x4 = (const f32x4*)d_in[0];
    const int* indices = (const int*)d_in[1];
    f32x4* out4 = (f32x4*)d_out;

    const int n  = in_sizes[0] / D;   // 100000
    const int n4 = in_sizes[1];       // 400000

    // ws layout (64B-aligned fields)
    size_t off_counts  = 0;                                   // n ints
    size_t off_ovfcnt  = (size_t)((n * 4 + 63) / 64) * 64;    // 1 int
    size_t off_ovf     = off_ovfcnt + 64;                     // OVF_CAP ints
    size_t off_buckets = off_ovf + (size_t)OVF_CAP * 4;       // n*CAP ints
    size_t need = off_buckets + (size_t)n * CAP * 4;

    dim3 block(256);

    if (ws_size < need) {
        // scratch too small: forward gather fallback
        collect_fwd_kernel<<<dim3((n + 3) / 4), block, 0, stream>>>(x4, indices, out4, n);
        return;
    }

    char* ws = (char*)d_ws;
    int* counts  = (int*)(ws + off_counts);
    int* ovf_cnt = (int*)(ws + off_ovfcnt);
    int* ovf     = (int*)(ws + off_ovf);
    int* buckets = (int*)(ws + off_buckets);

    zero_counts_kernel<<<dim3((n + 255) / 256), block, 0, stream>>>(counts, ovf_cnt, n);
    build_buckets_kernel<<<dim3((n4 + 255) / 256), block, 0, stream>>>(
        indices, counts, buckets, ovf, ovf_cnt, n4);
    scatter_kernel<<<dim3((n + 3) / 4), block, 0, stream>>>(
        x4, indices, counts, buckets, out4, n);
    overflow_fixup_kernel<<<dim3(8), block, 0, stream>>>(
        x4, indices, ovf, ovf_cnt, out4);
}